// Round 1
// baseline (1030.559 us; speedup 1.0000x reference)
//
#include <hip/hip_runtime.h>
#include <math.h>

// ---------------------------------------------------------------------------
// CommunityTrustGNN: 2-layer GraphSAGE (mean agg) + trust MLP head
// N=100000 nodes, E=1600000 edges, dims 64 -> 64 -> 32 -> (16 -> 1)
//
// Key restructuring: segment-mean commutes with the per-node linear map, so
// layer 2 scatters p = relu(h1) @ Wl2 (32 floats/edge) instead of h1 (64).
// ---------------------------------------------------------------------------

// Kernel 1: aggregate x over edges + degree count.
// One wave (64 lanes) per edge; lane = feature dim.
__global__ __launch_bounds__(256) void k_scatter1(
    const int* __restrict__ src, const int* __restrict__ dst,
    const float* __restrict__ x, float* __restrict__ agg1,
    float* __restrict__ deg, int E)
{
    int e = blockIdx.x * 4 + (threadIdx.x >> 6);
    int d = threadIdx.x & 63;
    if (e >= E) return;
    int s = src[e];
    int t = dst[e];
    atomicAdd(&agg1[(size_t)t * 64 + d], x[(size_t)s * 64 + d]);
    if (d == 0) atomicAdd(&deg[t], 1.0f);
}

// Kernel 2: h1 = relu( (agg1/max(deg,1)) @ Wl1 + x @ Wr1 + b1 )
// One wave per node; lane j computes output feature j.
__global__ __launch_bounds__(256) void k_dense1(
    const float* __restrict__ agg1, const float* __restrict__ deg,
    const float* __restrict__ x,
    const float* __restrict__ Wl, const float* __restrict__ Wr,
    const float* __restrict__ b, float* __restrict__ h1, int N)
{
    __shared__ float sWl[64 * 64];
    __shared__ float sWr[64 * 64];
    for (int i = threadIdx.x; i < 64 * 64; i += 256) {
        sWl[i] = Wl[i];
        sWr[i] = Wr[i];
    }
    __syncthreads();

    int n = blockIdx.x * 4 + (threadIdx.x >> 6);
    int j = threadIdx.x & 63;
    if (n >= N) return;

    float invd = 1.0f / fmaxf(deg[n], 1.0f);
    float a  = agg1[(size_t)n * 64 + j] * invd;  // this lane's dim of agg row
    float xv = x[(size_t)n * 64 + j];            // this lane's dim of x row
    float acc = b[j];
    #pragma unroll
    for (int k = 0; k < 64; ++k) {
        float ak = __shfl(a, k);
        float xk = __shfl(xv, k);
        acc += ak * sWl[k * 64 + j] + xk * sWr[k * 64 + j];
    }
    h1[(size_t)n * 64 + j] = fmaxf(acc, 0.0f);
}

// Kernel 3: p = h1 @ Wl2   (to be scattered over edges)
//           q = h1 @ Wr2 + b2  (root/residual term)
// One wave per node; lanes 0..31 -> p, lanes 32..63 -> q.
__global__ __launch_bounds__(256) void k_dense2pre(
    const float* __restrict__ h1,
    const float* __restrict__ Wl, const float* __restrict__ Wr,
    const float* __restrict__ b,
    float* __restrict__ p, float* __restrict__ q, int N)
{
    __shared__ float sWl[64 * 32];
    __shared__ float sWr[64 * 32];
    for (int i = threadIdx.x; i < 64 * 32; i += 256) {
        sWl[i] = Wl[i];
        sWr[i] = Wr[i];
    }
    __syncthreads();

    int n = blockIdx.x * 4 + (threadIdx.x >> 6);
    int lane = threadIdx.x & 63;
    if (n >= N) return;
    int j = lane & 31;
    int half = lane >> 5;

    float hv = h1[(size_t)n * 64 + lane];   // full 64-dim row spread over wave
    const float* W = half ? sWr : sWl;
    float acc = 0.0f;
    #pragma unroll
    for (int k = 0; k < 64; ++k) {
        float hk = __shfl(hv, k);
        acc += hk * W[k * 32 + j];
    }
    if (half) q[(size_t)n * 32 + j] = acc + b[j];
    else      p[(size_t)n * 32 + j] = acc;
}

// Kernel 4: scatter p over edges into agg2. 2 edges per wave, 32 dims each.
__global__ __launch_bounds__(256) void k_scatter2(
    const int* __restrict__ src, const int* __restrict__ dst,
    const float* __restrict__ p, float* __restrict__ agg2, int E)
{
    int idx = blockIdx.x * 256 + threadIdx.x;
    int e = idx >> 5;
    int d = idx & 31;
    if (e >= E) return;
    int s = src[e];
    int t = dst[e];
    atomicAdd(&agg2[(size_t)t * 32 + d], p[(size_t)s * 32 + d]);
}

// Kernel 5: h = agg2/max(deg,1) + q  -> out_h
//           t16 = relu(h @ Wt1 + bt1); trust = sigmoid(t16 @ Wt2 + bt2)
// One wave per node.
__global__ __launch_bounds__(256) void k_final(
    const float* __restrict__ agg2, const float* __restrict__ deg,
    const float* __restrict__ q,
    const float* __restrict__ Wt1, const float* __restrict__ bt1,
    const float* __restrict__ Wt2, const float* __restrict__ bt2,
    float* __restrict__ out_h, float* __restrict__ out_trust, int N)
{
    __shared__ float sW1[32 * 16];
    __shared__ float sb1[16];
    __shared__ float sW2[16];
    for (int i = threadIdx.x; i < 32 * 16; i += 256) sW1[i] = Wt1[i];
    if (threadIdx.x < 16) {
        sb1[threadIdx.x] = bt1[threadIdx.x];
        sW2[threadIdx.x] = Wt2[threadIdx.x];
    }
    __syncthreads();

    int n = blockIdx.x * 4 + (threadIdx.x >> 6);
    int lane = threadIdx.x & 63;
    if (n >= N) return;
    int j = lane & 31;

    float invd = 1.0f / fmaxf(deg[n], 1.0f);
    // lanes 0..31 hold the h row; lanes 32..63 compute a redundant copy
    float h = agg2[(size_t)n * 32 + j] * invd + q[(size_t)n * 32 + j];
    if (lane < 32) out_h[(size_t)n * 32 + j] = h;

    // t_i = relu( sum_j h_j * Wt1[j][i] + bt1[i] ), i = lane & 15
    int i16 = lane & 15;
    float t = sb1[i16];
    #pragma unroll
    for (int k = 0; k < 32; ++k) {
        float hk = __shfl(h, k);   // lanes 0..31 hold valid h
        t += hk * sW1[k * 16 + i16];
    }
    t = fmaxf(t, 0.0f);

    // trust = sigmoid( sum_i t_i * Wt2[i] + bt2 )
    float z = t * sW2[i16];
    z += __shfl_xor(z, 1);
    z += __shfl_xor(z, 2);
    z += __shfl_xor(z, 4);
    z += __shfl_xor(z, 8);
    if (lane == 0) {
        float v = z + bt2[0];
        out_trust[n] = 1.0f / (1.0f + expf(-v));
    }
}

extern "C" void kernel_launch(void* const* d_in, const int* in_sizes, int n_in,
                              void* d_out, int out_size, void* d_ws, size_t ws_size,
                              hipStream_t stream)
{
    const float* x   = (const float*)d_in[0];
    const int*   ei  = (const int*)d_in[1];   // jnp.int64 under x64-disabled JAX -> int32
    const float* Wl1 = (const float*)d_in[2];
    const float* Wr1 = (const float*)d_in[3];
    const float* b1  = (const float*)d_in[4];
    const float* Wl2 = (const float*)d_in[5];
    const float* Wr2 = (const float*)d_in[6];
    const float* b2  = (const float*)d_in[7];
    const float* Wt1 = (const float*)d_in[8];
    const float* bt1 = (const float*)d_in[9];
    const float* Wt2 = (const float*)d_in[10];
    const float* bt2 = (const float*)d_in[11];

    const int N = in_sizes[0] / 64;   // 100000
    const int E = in_sizes[1] / 2;    // 1600000
    const int* src = ei;
    const int* dst = ei + E;

    // Workspace layout (floats). agg1|agg2|deg contiguous -> single memset.
    float* ws   = (float*)d_ws;
    float* agg1 = ws;                          // N*64
    float* agg2 = agg1 + (size_t)N * 64;       // N*32
    float* deg  = agg2 + (size_t)N * 32;       // N
    float* h1   = deg + N;                     // N*64
    float* p    = h1 + (size_t)N * 64;         // N*32
    float* q    = p + (size_t)N * 32;          // N*32
    // total: N*(64+32+1+64+32+32) = 225*N floats = 90 MB

    hipMemsetAsync(agg1, 0, (size_t)N * (64 + 32 + 1) * sizeof(float), stream);

    k_scatter1 <<<(E + 3) / 4,       256, 0, stream>>>(src, dst, x, agg1, deg, E);
    k_dense1   <<<(N + 3) / 4,       256, 0, stream>>>(agg1, deg, x, Wl1, Wr1, b1, h1, N);
    k_dense2pre<<<(N + 3) / 4,       256, 0, stream>>>(h1, Wl2, Wr2, b2, p, q, N);
    k_scatter2 <<<(E * 32 + 255) / 256, 256, 0, stream>>>(src, dst, p, agg2, E);

    float* out_h     = (float*)d_out;
    float* out_trust = out_h + (size_t)N * 32;
    k_final    <<<(N + 3) / 4,       256, 0, stream>>>(agg2, deg, q, Wt1, bt1, Wt2, bt2,
                                                       out_h, out_trust, N);
}